// Round 10
// baseline (337.248 us; speedup 1.0000x reference)
//
#include <hip/hip_runtime.h>
#include <hip/hip_bf16.h>
#include <stdint.h>

typedef __attribute__((ext_vector_type(8))) __bf16 bf16x8;
typedef __attribute__((ext_vector_type(4))) float f32x4;

#define BM 256
#define BN 256
#define BKT 32              // K per ring slot
#define SLOT 16384          // 256 rows x 32 cols x 2B
// ring-5: LDS = 5*(16K+16K) = 160 KiB (CU max); stage distance 3-4 tiles

// ---------------- NVFP4 quantize-dequantize (factored: no global scale) ----------------

__device__ __forceinline__ float fp8_e4m3_rne(float x) {
  if (x < 0.015625f) {                       // below min normal 2^-6: subnormal grid 2^-9
    return rintf(x * 512.0f) * 0.001953125f;
  }
  uint32_t u = __float_as_uint(x);
  uint32_t keep = u & 0xFFF00000u;
  uint32_t rem  = u & 0x000FFFFFu;
  uint32_t lsb  = (u >> 20) & 1u;
  if (rem > 0x80000u || (rem == 0x80000u && lsb)) keep += 0x100000u;
  return __uint_as_float(keep);
}

__device__ __forceinline__ float snap_lvl(float a) {
  if (a > 5.0f)  return 6.0f;
  if (a > 3.5f)  return 4.0f;
  if (a > 2.5f)  return 3.0f;
  if (a > 1.75f) return 2.0f;
  if (a > 1.25f) return 1.5f;
  if (a > 0.75f) return 1.0f;
  if (a > 0.25f) return 0.5f;
  return 0.0f;
}

__global__ __launch_bounds__(256) void quant_nvfp4(
    const float* __restrict__ in, unsigned short* __restrict__ out,
    const float* __restrict__ gsp, int nblk) {
  int b = blockIdx.x * 256 + threadIdx.x;
  if (b >= nblk) return;
  float gs = gsp[0];
  const float4* p = reinterpret_cast<const float4*>(in) + (size_t)b * 4;
  float v[16];
#pragma unroll
  for (int i = 0; i < 4; ++i) {
    float4 t4 = p[i];
    v[i * 4 + 0] = t4.x; v[i * 4 + 1] = t4.y;
    v[i * 4 + 2] = t4.z; v[i * 4 + 3] = t4.w;
  }
  float amax = 0.0f;
#pragma unroll
  for (int i = 0; i < 16; ++i) amax = fmaxf(amax, fabsf(v[i]));
  float bs8 = fp8_e4m3_rne(amax / (6.0f * gs));
  float scale = fmaxf(bs8 * gs, 1e-12f);
  unsigned short o[16];
#pragma unroll
  for (int i = 0; i < 16; ++i) {
    float q = v[i] / scale;
    float a = fminf(fabsf(q), 6.0f);
    float val = copysignf(snap_lvl(a) * bs8, q);
    o[i] = (unsigned short)(__float_as_uint(val) >> 16);
  }
  uint4 w0 = make_uint4((uint32_t)o[0] | ((uint32_t)o[1] << 16),
                        (uint32_t)o[2] | ((uint32_t)o[3] << 16),
                        (uint32_t)o[4] | ((uint32_t)o[5] << 16),
                        (uint32_t)o[6] | ((uint32_t)o[7] << 16));
  uint4 w1 = make_uint4((uint32_t)o[8]  | ((uint32_t)o[9]  << 16),
                        (uint32_t)o[10] | ((uint32_t)o[11] << 16),
                        (uint32_t)o[12] | ((uint32_t)o[13] << 16),
                        (uint32_t)o[14] | ((uint32_t)o[15] << 16));
  uint4* op = reinterpret_cast<uint4*>(out + (size_t)b * 16);
  op[0] = w0;
  op[1] = w1;
}

// ---------------- bf16 GEMM, C = A * B^T ; 256x256 tile, ring-5, compiler-scheduled ----------------

__device__ __forceinline__ void async_lds16(const void* g, void* l) {
  __builtin_amdgcn_global_load_lds((__attribute__((address_space(1))) void*)(g),
                                   (__attribute__((address_space(3))) void*)(l),
                                   16, 0, 0);
}

#define SB asm volatile("" ::: "memory")
#define VMC(S) asm volatile("s_waitcnt vmcnt(" S ")" ::: "memory")

#define STAGE_TILE(s, so) {                                                    \
    char* _la = (char*)As + (so);                                              \
    char* _lb = (char*)Bs + (so);                                              \
    async_lds16(pA0 + (size_t)(s) * BKT, _la + lo0);                           \
    async_lds16(pB0 + (size_t)(s) * BKT, _lb + lo0);                           \
    async_lds16(pA1 + (size_t)(s) * BKT, _la + lo1);                           \
    async_lds16(pB1 + (size_t)(s) * BKT, _lb + lo1);                           \
  }

// plain C++ reads + plain MFMA: compiler schedules/interleaves with counted lgkm
#define CTILE(SOFF) do {                                                       \
    bf16x8 bfr[4], afr[8];                                                     \
    _Pragma("unroll") for (int ni = 0; ni < 4; ++ni)                           \
      bfr[ni] = *(const bf16x8*)((const char*)Bs + offB[ni] + (SOFF));         \
    _Pragma("unroll") for (int mi = 0; mi < 8; ++mi)                           \
      afr[mi] = *(const bf16x8*)((const char*)As + offA[mi] + (SOFF));         \
    _Pragma("unroll") for (int mi = 0; mi < 8; ++mi)                           \
      _Pragma("unroll") for (int ni = 0; ni < 4; ++ni)                         \
        acc[mi][ni] = __builtin_amdgcn_mfma_f32_16x16x32_bf16(                 \
            afr[mi], bfr[ni], acc[mi][ni], 0, 0, 0);                           \
  } while (0)

__global__ __launch_bounds__(512, 2) void gemm_bt_bf16(
    const unsigned short* __restrict__ A, const unsigned short* __restrict__ B,
    const float* __restrict__ bias, const float* __restrict__ gsx,
    const float* __restrict__ gsw, float* __restrict__ C,
    int M, int N, int K) {
  __shared__ __align__(16) unsigned short As[5 * 8192];   // 80 KiB
  __shared__ __align__(16) unsigned short Bs[5 * 8192];   // 80 KiB

  const int t = threadIdx.x;
  const int l = t & 63;
  const int w = t >> 6;
  const int wm = w >> 2, wn = w & 3;     // 2x4 waves; wave tile = 128(M) x 64(N)

  // bijective XCD swizzle (nwg = 512, divisible by 8)
  const int nbn = N / BN;
  const int nwg = (M / BM) * nbn;
  const int cpx = nwg >> 3;
  int bid = blockIdx.x;
  int logical = (bid & 7) * cpx + (bid >> 3);
  const int bm = logical / nbn, bn = logical % nbn;
  const int brow = bm * BM, bcol = bn * BN;

  // staging: linear LDS dest, inverse-swizzled global source (involution q^(((q>>7)&3)<<4))
  unsigned int b0 = (unsigned int)t * 16u;
  unsigned int b1 = b0 + 8192u;
  unsigned int bp0 = b0 ^ (((b0 >> 7) & 3u) << 4);
  unsigned int bp1 = b1 ^ (((b1 >> 7) & 3u) << 4);
  const unsigned int lo0 = b0, lo1 = b1;
  const unsigned short* pA0 = A + (size_t)(brow + (bp0 >> 6)) * K + ((bp0 & 63u) >> 1);
  const unsigned short* pA1 = A + (size_t)(brow + (bp1 >> 6)) * K + ((bp1 & 63u) >> 1);
  const unsigned short* pB0 = B + (size_t)(bcol + (bp0 >> 6)) * K + ((bp0 & 63u) >> 1);
  const unsigned short* pB1 = B + (size_t)(bcol + (bp1 >> 6)) * K + ((bp1 & 63u) >> 1);

  // swizzled fragment read byte-offsets (within a slot)
  unsigned int offA[8], offB[4];
#pragma unroll
  for (int mi = 0; mi < 8; ++mi) {
    unsigned int r = wm * 128 + mi * 16 + (l & 15);
    unsigned int q = r * 64 + ((l >> 4) << 4);
    offA[mi] = q ^ (((q >> 7) & 3u) << 4);
  }
#pragma unroll
  for (int ni = 0; ni < 4; ++ni) {
    unsigned int r = wn * 64 + ni * 16 + (l & 15);
    unsigned int q = r * 64 + ((l >> 4) << 4);
    offB[ni] = q ^ (((q >> 7) & 3u) << 4);
  }

  f32x4 acc[8][4] = {};

  // prologue: stage tiles 0,1,2 into slots 0,1,2 (12 units in flight)
  STAGE_TILE(0, 0);
  STAGE_TILE(1, SLOT);
  STAGE_TILE(2, 2 * SLOT);

  // windows w=0..61: tiles {2w,2w+1} in slots {sa,sa+1}; stage 2w+3 -> sa+3, 2w+4 -> sa+4.
  // Gate: vmcnt(4) confirms tiles 2w,2w+1 (outstanding at gate = {2w+1:4, 2w+2:4}).
  // WAR: written slots sa+3,sa+4 disjoint from read slots; their old readers
  // returned before the previous window's barrier.
  int sa = 0;
#pragma unroll 1
  for (int w2 = 0; w2 < 62; ++w2) {
    int T = 2 * w2;
    int sb = sa + 1; if (sb >= 5) sb -= 5;
    int s3 = sa + 3; if (s3 >= 5) s3 -= 5;
    int s4 = sa + 4; if (s4 >= 5) s4 -= 5;
    SB; VMC("4"); __builtin_amdgcn_s_barrier(); SB;
    STAGE_TILE(T + 3, s3 * SLOT);
    CTILE(sa * SLOT);
    STAGE_TILE(T + 4, s4 * SLOT);
    CTILE(sb * SLOT);
    sa += 2; if (sa >= 5) sa -= 5;
  }
  // w62: tiles 124 (slot 4), 125 (slot 0); stage tile 127 -> slot 2
  SB; VMC("4"); __builtin_amdgcn_s_barrier(); SB;
  STAGE_TILE(127, 2 * SLOT);
  CTILE(4 * SLOT);
  CTILE(0 * SLOT);
  // w63: tiles 126 (slot 1), 127 (slot 2); drain
  SB; VMC("0"); __builtin_amdgcn_s_barrier(); SB;
  CTILE(1 * SLOT);
  CTILE(2 * SLOT);

  // ---- epilogue ----
  const float gscale = gsx[0] * gsw[0];
  float bias_r[4];
#pragma unroll
  for (int ni = 0; ni < 4; ++ni)
    bias_r[ni] = bias[bcol + wn * 64 + ni * 16 + (l & 15)];
#pragma unroll
  for (int mi = 0; mi < 8; ++mi) {
#pragma unroll
    for (int ni = 0; ni < 4; ++ni) {
#pragma unroll
      for (int r = 0; r < 4; ++r) {
        int row = brow + wm * 128 + mi * 16 + (l >> 4) * 4 + r;
        int col = bcol + wn * 64 + ni * 16 + (l & 15);
        C[(size_t)row * N + col] = acc[mi][ni][r] * gscale + bias_r[ni];
      }
    }
  }
}

// ---------------- launch ----------------

extern "C" void kernel_launch(void* const* d_in, const int* in_sizes, int n_in,
                              void* d_out, int out_size, void* d_ws, size_t ws_size,
                              hipStream_t stream) {
  const float* x    = (const float*)d_in[0];
  const float* wgt  = (const float*)d_in[1];
  const float* bias = (const float*)d_in[2];
  const float* isc  = (const float*)d_in[3];
  const float* wsc  = (const float*)d_in[4];
  float* out = (float*)d_out;

  const int N = in_sizes[2];            // 4096
  const int K = in_sizes[1] / N;        // 4096
  const int M = in_sizes[0] / K;        // 8192

  unsigned short* Aq = (unsigned short*)d_ws;
  unsigned short* Bq = Aq + (size_t)M * K;

  int nblkA = M * K / 16;
  quant_nvfp4<<<(nblkA + 255) / 256, 256, 0, stream>>>(x, Aq, isc, nblkA);
  int nblkB = N * K / 16;
  quant_nvfp4<<<(nblkB + 255) / 256, 256, 0, stream>>>(wgt, Bq, wsc, nblkB);

  dim3 grid((M / BM) * (N / BN));
  gemm_bt_bf16<<<grid, 512, 0, stream>>>(Aq, Bq, bias, isc, wsc, out, M, N, K);
}

// Round 11
// 281.742 us; speedup vs baseline: 1.1970x; 1.1970x over previous
//
#include <hip/hip_runtime.h>
#include <hip/hip_bf16.h>
#include <stdint.h>

typedef __attribute__((ext_vector_type(8))) __bf16 bf16x8;
typedef __attribute__((ext_vector_type(4))) float f32x4;
typedef __attribute__((ext_vector_type(4))) unsigned int u32x4;

#define BM 256
#define BN 256
#define BKT 32              // K per tile
#define SLOT 16384          // A slot: 256 rows x 32 k x 2B
// A ring-3 slots = 48 KiB LDS. B never touches LDS (packed-fragment direct loads).

// ---------------- NVFP4 quantize-dequantize (factored: no global scale) ----------------

__device__ __forceinline__ float fp8_e4m3_rne(float x) {
  if (x < 0.015625f) {
    return rintf(x * 512.0f) * 0.001953125f;
  }
  uint32_t u = __float_as_uint(x);
  uint32_t keep = u & 0xFFF00000u;
  uint32_t rem  = u & 0x000FFFFFu;
  uint32_t lsb  = (u >> 20) & 1u;
  if (rem > 0x80000u || (rem == 0x80000u && lsb)) keep += 0x100000u;
  return __uint_as_float(keep);
}

__device__ __forceinline__ float snap_lvl(float a) {
  if (a > 5.0f)  return 6.0f;
  if (a > 3.5f)  return 4.0f;
  if (a > 2.5f)  return 3.0f;
  if (a > 1.75f) return 2.0f;
  if (a > 1.25f) return 1.5f;
  if (a > 0.75f) return 1.0f;
  if (a > 0.25f) return 0.5f;
  return 0.0f;
}

__device__ __forceinline__ void quant16(const float* __restrict__ src, float gs,
                                        unsigned short* o) {
  float v[16];
#pragma unroll
  for (int i = 0; i < 4; ++i) {
    float4 t4 = reinterpret_cast<const float4*>(src)[i];
    v[i * 4 + 0] = t4.x; v[i * 4 + 1] = t4.y;
    v[i * 4 + 2] = t4.z; v[i * 4 + 3] = t4.w;
  }
  float amax = 0.0f;
#pragma unroll
  for (int i = 0; i < 16; ++i) amax = fmaxf(amax, fabsf(v[i]));
  float bs8 = fp8_e4m3_rne(amax / (6.0f * gs));
  float scale = fmaxf(bs8 * gs, 1e-12f);
#pragma unroll
  for (int i = 0; i < 16; ++i) {
    float q = v[i] / scale;
    float a = fminf(fabsf(q), 6.0f);
    float val = copysignf(snap_lvl(a) * bs8, q);
    o[i] = (unsigned short)(__float_as_uint(val) >> 16);
  }
}

// A: row-major bf16 (for LDS staging)
__global__ __launch_bounds__(256) void quant_nvfp4(
    const float* __restrict__ in, unsigned short* __restrict__ out,
    const float* __restrict__ gsp, int nblk) {
  int b = blockIdx.x * 256 + threadIdx.x;
  if (b >= nblk) return;
  unsigned short o[16];
  quant16(in + (size_t)b * 16, gsp[0], o);
  uint4 w0 = make_uint4((uint32_t)o[0] | ((uint32_t)o[1] << 16),
                        (uint32_t)o[2] | ((uint32_t)o[3] << 16),
                        (uint32_t)o[4] | ((uint32_t)o[5] << 16),
                        (uint32_t)o[6] | ((uint32_t)o[7] << 16));
  uint4 w1 = make_uint4((uint32_t)o[8]  | ((uint32_t)o[9]  << 16),
                        (uint32_t)o[10] | ((uint32_t)o[11] << 16),
                        (uint32_t)o[12] | ((uint32_t)o[13] << 16),
                        (uint32_t)o[14] | ((uint32_t)o[15] << 16));
  uint4* op = reinterpret_cast<uint4*>(out + (size_t)b * 16);
  op[0] = w0;
  op[1] = w1;
}

// B: packed MFMA-fragment layout PB[n16][T][lane][8]:
//   element (n, k) -> PB[n/16][k/32][((k%32)/8)*16 + n%16][k%8]
// so lane l's 16x16x32 B-fragment (n16, T) is ONE contiguous 16B chunk at
//   byte ((n16*KT + T)*64 + l)*16  -> coalesced global_load_dwordx4.
__global__ __launch_bounds__(256) void quant_packB(
    const float* __restrict__ in, unsigned short* __restrict__ out,
    const float* __restrict__ gsp, int K, int nblk) {
  int t = blockIdx.x * 256 + threadIdx.x;
  if (t >= nblk) return;
  const int K16 = K >> 4;
  int nr   = t & 15;
  int rest = t >> 4;
  int kb   = rest % K16;
  int n16  = rest / K16;
  int row  = n16 * 16 + nr;
  unsigned short o[16];
  quant16(in + (size_t)row * K + (size_t)kb * 16, gsp[0], o);
  const int KT = K >> 5;
  size_t u0 = ((size_t)(n16 * KT + (kb >> 1)) * 64 + (kb & 1) * 32 + nr) * 8;
  uint4 w0 = make_uint4((uint32_t)o[0] | ((uint32_t)o[1] << 16),
                        (uint32_t)o[2] | ((uint32_t)o[3] << 16),
                        (uint32_t)o[4] | ((uint32_t)o[5] << 16),
                        (uint32_t)o[6] | ((uint32_t)o[7] << 16));
  uint4 w1 = make_uint4((uint32_t)o[8]  | ((uint32_t)o[9]  << 16),
                        (uint32_t)o[10] | ((uint32_t)o[11] << 16),
                        (uint32_t)o[12] | ((uint32_t)o[13] << 16),
                        (uint32_t)o[14] | ((uint32_t)o[15] << 16));
  *reinterpret_cast<uint4*>(out + u0)       = w0;   // k-half 0 (lane group +0)
  *reinterpret_cast<uint4*>(out + u0 + 128) = w1;   // k-half 1 (lane group +16)
}

// ---------------- bf16 GEMM: A via LDS (ring-3), B direct packed-fragment loads ----------------

__device__ __forceinline__ void async_lds16(const void* g, void* l) {
  __builtin_amdgcn_global_load_lds((__attribute__((address_space(1))) void*)(g),
                                   (__attribute__((address_space(3))) void*)(l),
                                   16, 0, 0);
}

#define DSR(dst, a) asm volatile("ds_read_b128 %0, %1" : "=v"(dst) : "v"(a))
#define LGKM(N) do { asm volatile("s_waitcnt lgkmcnt(" #N ")" ::: "memory"); \
                     __builtin_amdgcn_sched_barrier(0); } while (0)
#define VMC(S) asm volatile("s_waitcnt vmcnt(" S ")" ::: "memory")
#define SCB __builtin_amdgcn_sched_barrier(0)
#define BCB(x) __builtin_bit_cast(bf16x8, x)

#define BLOAD(dst, ni, Tn) \
  asm volatile("global_load_dwordx4 %0, %1, off" \
               : "=v"(dst) : "v"(bAddr[ni] + (uint64_t)(Tn) * 1024))

#define MF4(mi, ar, Bc0, Bc1, Bc2, Bc3) do {                                   \
    acc[mi][0] = __builtin_amdgcn_mfma_f32_16x16x32_bf16(BCB(ar), BCB(Bc0), acc[mi][0], 0, 0, 0); \
    acc[mi][1] = __builtin_amdgcn_mfma_f32_16x16x32_bf16(BCB(ar), BCB(Bc1), acc[mi][1], 0, 0, 0); \
    acc[mi][2] = __builtin_amdgcn_mfma_f32_16x16x32_bf16(BCB(ar), BCB(Bc2), acc[mi][2], 0, 0, 0); \
    acc[mi][3] = __builtin_amdgcn_mfma_f32_16x16x32_bf16(BCB(ar), BCB(Bc3), acc[mi][3], 0, 0, 0); \
  } while (0)

// Steady tile T: gate vmcnt(2) confirms B(T) regs + Astg(T) (per-wave), barrier
// publishes slot T%3 to all waves. Then issue B(T+1) (private), Astg(T+2)
// (slot (T+2)%3, whose old readers drained at LGKM(0) in tile T-1), 8 ds_reads
// of A(T), and 32 MFMA threaded on counted lgkm.
#define GTILE(T, C0, C1, C2, C3, N0, N1, N2, N3, DOB, DOA, VMS) do {           \
    VMC(VMS); SCB;                                                             \
    __builtin_amdgcn_s_barrier(); SCB;                                         \
    if (DOB) { BLOAD(N0, 0, (T) + 1); BLOAD(N1, 1, (T) + 1);                   \
               BLOAD(N2, 2, (T) + 1); BLOAD(N3, 3, (T) + 1); }                 \
    SCB;                                                                       \
    if (DOA) {                                                                 \
      char* _la = (char*)As + (((T) + 2) % 3) * SLOT;                          \
      async_lds16(pA0 + (size_t)((T) + 2) * BKT, _la + lo0);                   \
      async_lds16(pA1 + (size_t)((T) + 2) * BKT, _la + lo1);                   \
    }                                                                          \
    SCB;                                                                       \
    {                                                                          \
      const unsigned soff = (unsigned)(((T) % 3) * SLOT);                      \
      u32x4 a0, a1, a2, a3, a4, a5, a6, a7;                                    \
      DSR(a0, adA[0] + soff); DSR(a1, adA[1] + soff);                          \
      DSR(a2, adA[2] + soff); DSR(a3, adA[3] + soff);                          \
      DSR(a4, adA[4] + soff); DSR(a5, adA[5] + soff);                          \
      DSR(a6, adA[6] + soff); DSR(a7, adA[7] + soff);                          \
      SCB;                                                                     \
      LGKM(7); __builtin_amdgcn_s_setprio(1); MF4(0, a0, C0, C1, C2, C3);      \
      LGKM(6); MF4(1, a1, C0, C1, C2, C3);                                     \
      LGKM(5); MF4(2, a2, C0, C1, C2, C3);                                     \
      LGKM(4); MF4(3, a3, C0, C1, C2, C3);                                     \
      LGKM(3); MF4(4, a4, C0, C1, C2, C3);                                     \
      LGKM(2); MF4(5, a5, C0, C1, C2, C3);                                     \
      LGKM(1); MF4(6, a6, C0, C1, C2, C3);                                     \
      LGKM(0); MF4(7, a7, C0, C1, C2, C3);                                     \
      __builtin_amdgcn_s_setprio(0); SCB;                                      \
    }                                                                          \
  } while (0)

__global__ __launch_bounds__(512, 2) void gemm_bt_bf16(
    const unsigned short* __restrict__ A, const unsigned short* __restrict__ PB,
    const float* __restrict__ bias, const float* __restrict__ gsx,
    const float* __restrict__ gsw, float* __restrict__ C,
    int M, int N, int K) {
  __shared__ __align__(16) unsigned short As[3 * 8192];   // 48 KiB, A ring-3

  const int t = threadIdx.x;
  const int l = t & 63;
  const int w = t >> 6;
  const int wm = w >> 2, wn = w & 3;     // 2x4 waves; wave tile = 128(M) x 64(N)
  const int KT = K >> 5;                 // 128

  // bijective XCD swizzle (nwg = 512, divisible by 8)
  const int nbn = N / BN;
  const int nwg = (M / BM) * nbn;
  const int cpx = nwg >> 3;
  int bid = blockIdx.x;
  int logical = (bid & 7) * cpx + (bid >> 3);
  const int bm = logical / nbn, bn = logical % nbn;
  const int brow = bm * BM, bcol = bn * BN;

  // A staging: linear LDS dest, inverse-swizzled global source (involution q^(((q>>7)&3)<<4))
  unsigned int b0 = (unsigned int)t * 16u;
  unsigned int b1 = b0 + 8192u;
  unsigned int bp0 = b0 ^ (((b0 >> 7) & 3u) << 4);
  unsigned int bp1 = b1 ^ (((b1 >> 7) & 3u) << 4);
  const unsigned int lo0 = b0, lo1 = b1;
  const unsigned short* pA0 = A + (size_t)(brow + (bp0 >> 6)) * K + ((bp0 & 63u) >> 1);
  const unsigned short* pA1 = A + (size_t)(brow + (bp1 >> 6)) * K + ((bp1 & 63u) >> 1);

  // swizzled A-fragment read addresses
  const unsigned baseAu = (unsigned)(uintptr_t)(&As[0]);
  unsigned int adA[8];
#pragma unroll
  for (int mi = 0; mi < 8; ++mi) {
    unsigned int r = wm * 128 + mi * 16 + (l & 15);
    unsigned int q = r * 64 + ((l >> 4) << 4);
    adA[mi] = baseAu + (q ^ (((q >> 7) & 3u) << 4));
  }

  // B packed-fragment base addresses (per lane), chunk (n16, T) at ((n16*KT+T)*64+l)*16
  uint64_t bAddr[4];
#pragma unroll
  for (int ni = 0; ni < 4; ++ni) {
    int n16 = (bcol >> 4) + wn * 4 + ni;
    bAddr[ni] = (uint64_t)(uintptr_t)PB + (((uint64_t)n16 * KT) * 64 + (uint64_t)l) * 16;
  }

  f32x4 acc[8][4] = {};
  u32x4 bP0, bP1, bP2, bP3;   // B set 0 (even tiles)
  u32x4 bQ0, bQ1, bQ2, bQ3;   // B set 1 (odd tiles)

  // prologue: Astg(0) -> slot0, B(0) -> set0, Astg(1) -> slot1
  async_lds16(pA0, (char*)As + lo0);
  async_lds16(pA1, (char*)As + lo1);
  SCB;
  BLOAD(bP0, 0, 0); BLOAD(bP1, 1, 0); BLOAD(bP2, 2, 0); BLOAD(bP3, 3, 0);
  SCB;
  async_lds16(pA0 + BKT, (char*)As + SLOT + lo0);
  async_lds16(pA1 + BKT, (char*)As + SLOT + lo1);
  SCB;

  // steady: 63 x 2 tiles (T=0..125); tail 126, 127
#pragma unroll 1
  for (int i = 0; i < 63; ++i) {
    const int T = 2 * i;
    GTILE(T,     bP0, bP1, bP2, bP3, bQ0, bQ1, bQ2, bQ3, 1, 1, "2");
    GTILE(T + 1, bQ0, bQ1, bQ2, bQ3, bP0, bP1, bP2, bP3, 1, 1, "2");
  }
  GTILE(126, bP0, bP1, bP2, bP3, bQ0, bQ1, bQ2, bQ3, 1, 0, "2");
  GTILE(127, bQ0, bQ1, bQ2, bQ3, bP0, bP1, bP2, bP3, 0, 0, "0");

  // ---- epilogue ----
  const float gscale = gsx[0] * gsw[0];
  float bias_r[4];
#pragma unroll
  for (int ni = 0; ni < 4; ++ni)
    bias_r[ni] = bias[bcol + wn * 64 + ni * 16 + (l & 15)];
#pragma unroll
  for (int mi = 0; mi < 8; ++mi) {
#pragma unroll
    for (int ni = 0; ni < 4; ++ni) {
#pragma unroll
      for (int r = 0; r < 4; ++r) {
        int row = brow + wm * 128 + mi * 16 + (l >> 4) * 4 + r;
        int col = bcol + wn * 64 + ni * 16 + (l & 15);
        C[(size_t)row * N + col] = acc[mi][ni][r] * gscale + bias_r[ni];
      }
    }
  }
}

// ---------------- launch ----------------

extern "C" void kernel_launch(void* const* d_in, const int* in_sizes, int n_in,
                              void* d_out, int out_size, void* d_ws, size_t ws_size,
                              hipStream_t stream) {
  const float* x    = (const float*)d_in[0];
  const float* wgt  = (const float*)d_in[1];
  const float* bias = (const float*)d_in[2];
  const float* isc  = (const float*)d_in[3];
  const float* wsc  = (const float*)d_in[4];
  float* out = (float*)d_out;

  const int N = in_sizes[2];            // 4096
  const int K = in_sizes[1] / N;        // 4096
  const int M = in_sizes[0] / K;        // 8192

  unsigned short* Aq = (unsigned short*)d_ws;
  unsigned short* Bq = Aq + (size_t)M * K;

  int nblkA = M * K / 16;
  quant_nvfp4<<<(nblkA + 255) / 256, 256, 0, stream>>>(x, Aq, isc, nblkA);
  int nblkB = N * K / 16;
  quant_packB<<<(nblkB + 255) / 256, 256, 0, stream>>>(wgt, Bq, wsc, K, nblkB);

  dim3 grid((M / BM) * (N / BN));
  gemm_bt_bf16<<<grid, 512, 0, stream>>>(Aq, Bq, bias, isc, wsc, out, M, N, K);
}